// Round 4
// baseline (70375.049 us; speedup 1.0000x reference)
//
#include <hip/hip_runtime.h>
#include <hip/hip_bf16.h>

#define NWG 256   // persistent workgroups == #CUs; each owns 4 hidden units
#define NTH 512   // 8 waves; wave w owns gate-rows 2w,2w+1; wave 7 is the poller
#define T1  8192  // S*W word steps
#define SS  64
#define WW  128

typedef unsigned long long u64;
typedef unsigned int u32x4 __attribute__((ext_vector_type(4)));

// ws layout (8B units): [0..2047] hbuf64 (2 slots x 1024 tagged h),
// [2048..67583] encs64 (64 x 1024 tagged), [67584..67839] part64 (256 tagged),
// [67840..67903] cells (8 cells, one per 64B line). memset 0 each call.

__device__ __forceinline__ u64 aload(const u64* p) {
  return __hip_atomic_load(p, __ATOMIC_RELAXED, __HIP_MEMORY_SCOPE_AGENT);
}
__device__ __forceinline__ void astore(u64* p, u64 v) {
  __hip_atomic_store(p, v, __ATOMIC_RELAXED, __HIP_MEMORY_SCOPE_AGENT);
}
__device__ __forceinline__ u64 pack(float v, unsigned tag) {
  return ((u64)tag << 32) | (u64)__float_as_uint(v);
}

// 16B L1+L2-bypass load (fresh from coherence point); early-clobber so the
// address pair survives the retry loop re-execution.
__device__ __forceinline__ u32x4 load16_bypass(const u64* p) {
  u32x4 r;
  asm volatile("global_load_dwordx4 %0, %1, off sc0 sc1\n\ts_waitcnt vmcnt(0)"
               : "=&v"(r) : "v"(p) : "memory");
  return r;
}

// one-shot tagged read of this thread's 2 columns (2*tid, 2*tid+1) + deposit.
// u64 little-endian: dwords = [val, tag]; v4 = [val0, tag0, val1, tag1].
#define READ2_VERIFY(BASE, TAG, DST) do {                                 \
    const u64* _q = (BASE) + ((size_t)tid << 1);                          \
    const unsigned _t = (unsigned)(TAG);                                  \
    u32x4 _r;                                                             \
    for (;;) { _r = load16_bypass(_q); if (_r.y == _t && _r.w == _t) break; } \
    (DST)[(tid << 1) + 0] = __uint_as_float(_r.x);                        \
    (DST)[(tid << 1) + 1] = __uint_as_float(_r.z);                        \
  } while (0)

// wave 7 polls the 8 counter cells (cells[c*8] >= 32*k), fans out via LDS go.
__device__ __forceinline__ void gate_wait(const u64* cells, unsigned k,
                                          int wv, int l, int* goP) {
  if (wv == 7) {
    const u64 need = (u64)k << 5;   // 32*k
    for (;;) {
      u64 cv = ~0ull;
      if (l < 8) cv = aload(cells + ((size_t)l << 3));
      if (__all((int)(cv >= need))) break;
    }
    if (l == 0)
      __hip_atomic_store(goP, (int)k, __ATOMIC_RELAXED, __HIP_MEMORY_SCOPE_WORKGROUP);
  } else {
    while (__hip_atomic_load(goP, __ATOMIC_RELAXED, __HIP_MEMORY_SCOPE_WORKGROUP) < (int)k) {}
  }
}

__global__ __launch_bounds__(NTH) __attribute__((amdgpu_waves_per_eu(2, 2)))
void lstm_hier_attn(const float* __restrict__ xin,
                    const float* __restrict__ h1_0, const float* __restrict__ c1_0,
                    const float* __restrict__ h2_0, const float* __restrict__ c2_0,
                    const float* __restrict__ Wih1, const float* __restrict__ Whh1,
                    const float* __restrict__ bih1, const float* __restrict__ bhh1,
                    const float* __restrict__ Wih2, const float* __restrict__ Whh2,
                    const float* __restrict__ bih2, const float* __restrict__ bhh2,
                    const float* __restrict__ attw, const float* __restrict__ atts,
                    const float* __restrict__ Wf,   const float* __restrict__ bfb,
                    u64* hbuf64, u64* encs64, u64* part64, u64* cells, float* out)
{
  const int wid = blockIdx.x;
  const int tid = threadIdx.x;
  const int wv  = tid >> 6;   // wave id 0..7
  const int l   = tid & 63;   // lane
  const int u0  = wid << 2;   // first hidden unit owned by this WG

  __shared__ float wih_lds[16 * 1024];   // 64KB: x-weights (16 gate rows x 1024)
  __shared__ float h_lds[1024];
  __shared__ float e_lds[1024];
  __shared__ float aw_lds[WW];
  __shared__ float as_lds[SS];
  __shared__ float g_lds[16];
  __shared__ float c_lds[4];
  __shared__ float enc_lds[4];
  __shared__ float row_lds[4];
  __shared__ int go;

  if (tid == 0) {   // one-time softmaxes
    go = 0;
    float m = -1e30f;
    for (int i = 0; i < WW; ++i) m = fmaxf(m, attw[i]);
    float ssum = 0.f;
    for (int i = 0; i < WW; ++i) { float e = __expf(attw[i] - m); aw_lds[i] = e; ssum += e; }
    float inv = 1.f / ssum;
    for (int i = 0; i < WW; ++i) aw_lds[i] *= inv;
    m = -1e30f;
    for (int i = 0; i < SS; ++i) m = fmaxf(m, atts[i]);
    ssum = 0.f;
    for (int i = 0; i < SS; ++i) { float e = __expf(atts[i] - m); as_lds[i] = e; ssum += e; }
    inv = 1.f / ssum;
    for (int i = 0; i < SS; ++i) as_lds[i] *= inv;
  }
  if (tid < 4) {
    c_lds[tid]   = c1_0[u0 + tid];
    enc_lds[tid] = 0.f;
    row_lds[tid] = 0.f;
  }

  // wih1 -> LDS (once). local gate-row r (0..15): gate=r>>2, unit j=r&3,
  // global row = (r>>2)*1024 + u0 + (r&3).
  for (int q = 0; q < 32; ++q) {
    const int idx = (q << 9) + tid;          // 0..16383
    const int r = idx >> 10, col = idx & 1023;
    const int grow = ((r >> 2) << 10) + u0 + (r & 3);
    wih_lds[idx] = Wih1[(size_t)grow * 1024 + col];
  }

  // whh1 -> registers (32 floats/thread): rows r0=2wv, r1=2wv+1, cols jj*64+l
  float whh[2][16], bias[2];
#pragma unroll
  for (int t = 0; t < 2; ++t) {
    const int r    = (wv << 1) + t;
    const int grow = ((r >> 2) << 10) + u0 + (r & 3);
    bias[t] = bih1[grow] + bhh1[grow];
    const float* phh = Whh1 + (size_t)grow * 1024 + l;
#pragma unroll
    for (int jj = 0; jj < 16; ++jj) whh[t][jj] = phh[jj * 64];
  }
#pragma unroll
  for (int t = 0; t < 2; ++t)
#pragma unroll
    for (int jj = 0; jj < 16; ++jj) asm volatile("" : "+v"(whh[t][jj]));
  __syncthreads();

  const int r0 = (wv << 1), r1 = r0 + 1;

  // ======================= layer 1: 8192 word steps =======================
  for (int k = 0; k < T1; ++k) {
    // x-row load + x-partial from LDS wih — entirely pre-gate (off critical path)
    const float* xrow = xin + (size_t)k * 1024 + l;
    float xv[16];
#pragma unroll
    for (int jj = 0; jj < 16; ++jj) xv[jj] = xrow[jj * 64];
    float xa0 = 0.f, xa1 = 0.f;
#pragma unroll
    for (int jj = 0; jj < 16; ++jj) {
      const float x = xv[jj];
      xa0 += wih_lds[(r0 << 10) + (jj << 6) + l] * x;
      xa1 += wih_lds[(r1 << 10) + (jj << 6) + l] * x;
    }

    if (k > 0) {
      gate_wait(cells, (unsigned)k, wv, l, &go);
      READ2_VERIFY(hbuf64 + ((size_t)(k & 1) << 10), k, h_lds);
    } else {
      h_lds[tid]       = h1_0[tid];
      h_lds[512 + tid] = h1_0[512 + tid];
    }
    __syncthreads();   // B1: h_lds ready

    float a0 = xa0, a1 = xa1;
#pragma unroll
    for (int jj = 0; jj < 16; ++jj) {
      const float hv = h_lds[(jj << 6) + l];
      a0 += whh[0][jj] * hv; a1 += whh[1][jj] * hv;
    }
#pragma unroll
    for (int m = 1; m < 64; m <<= 1) {
      a0 += __shfl_xor(a0, m); a1 += __shfl_xor(a1, m);
    }
    if (l == 0) {
      g_lds[r0] = a0 + bias[0];
      g_lds[r1] = a1 + bias[1];
    }
    __syncthreads();   // B2: g_lds ready; all step-k LDS reads done
    if (tid < 4) {                       // torch gate order: i,f,g,o
      const int j = tid;
      const float ig = g_lds[0 + j], fg = g_lds[4 + j], gg = g_lds[8 + j], og = g_lds[12 + j];
      const float si = 1.f / (1.f + __expf(-ig));
      const float sf = 1.f / (1.f + __expf(-fg));
      const float so = 1.f / (1.f + __expf(-og));
      const float c  = sf * c_lds[j] + si * tanhf(gg);
      const float h  = so * tanhf(c);
      c_lds[j] = c;
      const int wd = k & (WW - 1);
      float e = enc_lds[j] + aw_lds[wd] * h;          // enc = aw @ hs (online)
      u64* dst = hbuf64 + ((size_t)((k + 1) & 1) << 10);
      astore(&dst[u0 + j], pack(h, (unsigned)(k + 1)));
      if (wd == WW - 1) {
        astore(&encs64[((size_t)(k >> 7) << 10) + u0 + j], pack(e, (unsigned)((k >> 7) + 1)));
        e = 0.f;
      }
      enc_lds[j] = e;
    }
    if (tid == 0)   // completion signal; tags cover store/add completion races
      __hip_atomic_fetch_add(&cells[(size_t)(wid >> 5) << 3], 1ull,
                             __ATOMIC_RELAXED, __HIP_MEMORY_SCOPE_AGENT);
    // no trailing barrier: gate k+1 (cells>=32(k+1)) implies every WG finished
    // step-k reads, so h_lds/g_lds overwrites for k+1 are safe.
  }

  // ======================= layer 2: 64 sentence steps =======================
  for (int q = 0; q < 32; ++q) {         // wih2 -> LDS (safe: all wih reads done pre-B2 of k=8191)
    const int idx = (q << 9) + tid;
    const int r = idx >> 10, col = idx & 1023;
    const int grow = ((r >> 2) << 10) + u0 + (r & 3);
    wih_lds[idx] = Wih2[(size_t)grow * 1024 + col];
  }
#pragma unroll
  for (int t = 0; t < 2; ++t) {          // whh2 -> same registers
    const int r    = (wv << 1) + t;
    const int grow = ((r >> 2) << 10) + u0 + (r & 3);
    bias[t] = bih2[grow] + bhh2[grow];
    const float* phh = Whh2 + (size_t)grow * 1024 + l;
#pragma unroll
    for (int jj = 0; jj < 16; ++jj) whh[t][jj] = phh[jj * 64];
  }
#pragma unroll
  for (int t = 0; t < 2; ++t)
#pragma unroll
    for (int jj = 0; jj < 16; ++jj) asm volatile("" : "+v"(whh[t][jj]));
  if (tid < 4) c_lds[tid] = c2_0[u0 + tid];   // wave 0 only, after its last epilogue

  for (int s2 = 0; s2 < SS; ++s2) {
    const unsigned kg = (unsigned)(T1 + s2);
    // enc row: written back in layer 1, tag s2+1 — ancient, verify passes at once
    READ2_VERIFY(encs64 + ((size_t)s2 << 10), s2 + 1, e_lds);
    __syncthreads();   // e_lds ready (and, at s2=0, wih2/c2 ready)

    float xa0 = 0.f, xa1 = 0.f;
#pragma unroll
    for (int jj = 0; jj < 16; ++jj) {
      const float ev = e_lds[(jj << 6) + l];
      xa0 += wih_lds[(r0 << 10) + (jj << 6) + l] * ev;
      xa1 += wih_lds[(r1 << 10) + (jj << 6) + l] * ev;
    }

    // gate: s2==0 waits 32*8192 (all layer-1 reads done -> slot overwrite safe)
    gate_wait(cells, kg, wv, l, &go);
    if (s2 > 0) {
      READ2_VERIFY(hbuf64 + ((size_t)(kg & 1) << 10), kg, h_lds);
    } else {
      h_lds[tid]       = h2_0[tid];
      h_lds[512 + tid] = h2_0[512 + tid];
    }
    __syncthreads();   // B1

    float a0 = xa0, a1 = xa1;
#pragma unroll
    for (int jj = 0; jj < 16; ++jj) {
      const float hv = h_lds[(jj << 6) + l];
      a0 += whh[0][jj] * hv; a1 += whh[1][jj] * hv;
    }
#pragma unroll
    for (int m = 1; m < 64; m <<= 1) {
      a0 += __shfl_xor(a0, m); a1 += __shfl_xor(a1, m);
    }
    if (l == 0) {
      g_lds[r0] = a0 + bias[0];
      g_lds[r1] = a1 + bias[1];
    }
    __syncthreads();   // B2
    if (tid < 4) {
      const int j = tid;
      const float ig = g_lds[0 + j], fg = g_lds[4 + j], gg = g_lds[8 + j], og = g_lds[12 + j];
      const float si = 1.f / (1.f + __expf(-ig));
      const float sf = 1.f / (1.f + __expf(-fg));
      const float so = 1.f / (1.f + __expf(-og));
      const float c  = sf * c_lds[j] + si * tanhf(gg);
      const float h  = so * tanhf(c);
      c_lds[j] = c;
      row_lds[j] += as_lds[s2] * h;                    // row = asn @ hs2 (online)
      u64* dst = hbuf64 + ((size_t)((kg + 1) & 1) << 10);
      astore(&dst[u0 + j], pack(h, kg + 1));
    }
    if (tid == 0)
      __hip_atomic_fetch_add(&cells[(size_t)(wid >> 5) << 3], 1ull,
                             __ATOMIC_RELAXED, __HIP_MEMORY_SCOPE_AGENT);
  }

  // =================== final projection + sigmoid ===================
  if (tid == 0) {
    const float p = row_lds[0] * Wf[u0 + 0] + row_lds[1] * Wf[u0 + 1]
                  + row_lds[2] * Wf[u0 + 2] + row_lds[3] * Wf[u0 + 3];
    astore(&part64[wid], pack(p, 1u));
  }
  if (wid == 0) {
    if (tid < 256) {
      u64 a;
      for (;;) { a = aload(&part64[tid]); if ((unsigned)(a >> 32) == 1u) break; }
      h_lds[tid] = __uint_as_float((unsigned)a);
    }
    __syncthreads();
    if (wv == 0) {
      float p = h_lds[l] + h_lds[64 + l] + h_lds[128 + l] + h_lds[192 + l];
#pragma unroll
      for (int m = 1; m < 64; m <<= 1) p += __shfl_xor(p, m);
      if (l == 0) out[0] = 1.f / (1.f + __expf(-(p + bfb[0])));
    }
  }
}

extern "C" void kernel_launch(void* const* d_in, const int* in_sizes, int n_in,
                              void* d_out, int out_size, void* d_ws, size_t ws_size,
                              hipStream_t stream) {
  (void)in_sizes; (void)n_in; (void)out_size; (void)ws_size;
  const float* xin  = (const float*)d_in[0];
  const float* h1   = (const float*)d_in[1];
  const float* c1   = (const float*)d_in[2];
  const float* h2   = (const float*)d_in[3];
  const float* c2   = (const float*)d_in[4];
  const float* Wih1 = (const float*)d_in[5];
  const float* Whh1 = (const float*)d_in[6];
  const float* bih1 = (const float*)d_in[7];
  const float* bhh1 = (const float*)d_in[8];
  const float* Wih2 = (const float*)d_in[9];
  const float* Whh2 = (const float*)d_in[10];
  const float* bih2 = (const float*)d_in[11];
  const float* bhh2 = (const float*)d_in[12];
  const float* attw = (const float*)d_in[13];
  const float* atts = (const float*)d_in[14];
  const float* Wf   = (const float*)d_in[15];
  const float* bfb  = (const float*)d_in[16];

  u64* hbuf64 = (u64*)d_ws;                 // 2048 u64
  u64* encs64 = hbuf64 + 2048;              // 65536 u64
  u64* part64 = encs64 + 65536;             // 256 u64
  u64* cells  = part64 + 256;               // 64 u64 (8 cells, 64B apart)
  float* out  = (float*)d_out;

  // tags/counters must start at 0 every call — replay-safe, graph-capture legal
  hipMemsetAsync(d_ws, 0, (2048 + 65536 + 256 + 64) * sizeof(u64), stream);
  lstm_hier_attn<<<dim3(NWG), dim3(NTH), 0, stream>>>(
      xin, h1, c1, h2, c2, Wih1, Whh1, bih1, bhh1,
      Wih2, Whh2, bih2, bhh2, attw, atts, Wf, bfb,
      hbuf64, encs64, part64, cells, out);
}

// Round 5
// 67369.275 us; speedup vs baseline: 1.0446x; 1.0446x over previous
//
#include <hip/hip_runtime.h>
#include <hip/hip_bf16.h>

#define NWG 256   // persistent workgroups == #CUs; each owns 4 hidden units
#define NTH 512   // 8 waves; wave w owns gate-rows 2w,2w+1; wave 7 is the poller
#define T1  8192  // S*W word steps
#define SS  64
#define WW  128

typedef unsigned long long u64;
typedef unsigned int u32x4 __attribute__((ext_vector_type(4)));

// ws layout (8B units): [0..2047] hbuf64 (2 slots x 1024 tagged h),
// [2048..67583] encs64 (64 x 1024 tagged), [67584..67839] part64 (256 tagged),
// [67840..67903] cells (8 cells, one per 64B line). memset 0 each call.

__device__ __forceinline__ u64 aload(const u64* p) {
  return __hip_atomic_load(p, __ATOMIC_RELAXED, __HIP_MEMORY_SCOPE_AGENT);
}
__device__ __forceinline__ void astore(u64* p, u64 v) {
  __hip_atomic_store(p, v, __ATOMIC_RELAXED, __HIP_MEMORY_SCOPE_AGENT);
}
__device__ __forceinline__ u64 pack(float v, unsigned tag) {
  return ((u64)tag << 32) | (u64)__float_as_uint(v);
}

// 16B AGENT-scope load: sc1 only — bypasses the non-coherent XCD L2 but is
// served by the Infinity Cache (R4's sc0+sc1 = SYSTEM scope forced HBM round
// trips + dirty-line flushes: WRITE_SIZE doubled, 3x regression).
__device__ __forceinline__ u32x4 load16_agent(const u64* p) {
  u32x4 r;
  asm volatile("global_load_dwordx4 %0, %1, off sc1\n\ts_waitcnt vmcnt(0)"
               : "=&v"(r) : "v"(p) : "memory");
  return r;
}

// one-shot tagged read of this thread's 2 columns (2*tid, 2*tid+1) + deposit.
// u64 little-endian: dwords = [val, tag]; v4 = [val0, tag0, val1, tag1].
#define READ2_VERIFY(BASE, TAG, DST) do {                                 \
    const u64* _q = (BASE) + ((size_t)tid << 1);                          \
    const unsigned _t = (unsigned)(TAG);                                  \
    u32x4 _r;                                                             \
    for (;;) { _r = load16_agent(_q); if (__builtin_expect(_r.y == _t && _r.w == _t, 1)) break; } \
    (DST)[(tid << 1) + 0] = __uint_as_float(_r.x);                        \
    (DST)[(tid << 1) + 1] = __uint_as_float(_r.z);                        \
  } while (0)

// wave 7 polls the 8 counter cells (cells[c*8] >= 32*k), fans out via LDS go.
__device__ __forceinline__ void gate_wait(const u64* cells, unsigned k,
                                          int wv, int l, int* goP) {
  if (wv == 7) {
    const u64 need = (u64)k << 5;   // 32*k
    for (;;) {
      u64 cv = ~0ull;
      if (l < 8) cv = aload(cells + ((size_t)l << 3));
      if (__all((int)(cv >= need))) break;
    }
    if (l == 0)
      __hip_atomic_store(goP, (int)k, __ATOMIC_RELAXED, __HIP_MEMORY_SCOPE_WORKGROUP);
  } else {
    while (__hip_atomic_load(goP, __ATOMIC_RELAXED, __HIP_MEMORY_SCOPE_WORKGROUP) < (int)k) {}
  }
}

__global__ __launch_bounds__(NTH) __attribute__((amdgpu_waves_per_eu(2, 2)))
void lstm_hier_attn(const float* __restrict__ xin,
                    const float* __restrict__ h1_0, const float* __restrict__ c1_0,
                    const float* __restrict__ h2_0, const float* __restrict__ c2_0,
                    const float* __restrict__ Wih1, const float* __restrict__ Whh1,
                    const float* __restrict__ bih1, const float* __restrict__ bhh1,
                    const float* __restrict__ Wih2, const float* __restrict__ Whh2,
                    const float* __restrict__ bih2, const float* __restrict__ bhh2,
                    const float* __restrict__ attw, const float* __restrict__ atts,
                    const float* __restrict__ Wf,   const float* __restrict__ bfb,
                    u64* hbuf64, u64* encs64, u64* part64, u64* cells, float* out)
{
  const int wid = blockIdx.x;
  const int tid = threadIdx.x;
  const int wv  = tid >> 6;   // wave id 0..7
  const int l   = tid & 63;   // lane
  const int u0  = wid << 2;   // first hidden unit owned by this WG

  __shared__ float wih_lds[16 * 1024];   // 64KB: x-weights (16 gate rows x 1024)
  __shared__ float h_lds[1024];
  __shared__ float e_lds[1024];
  __shared__ float aw_lds[WW];
  __shared__ float as_lds[SS];
  __shared__ float g_lds[16];
  __shared__ float c_lds[4];
  __shared__ float enc_lds[4];
  __shared__ float row_lds[4];
  __shared__ int go;

  if (tid == 0) {   // one-time softmaxes
    go = 0;
    float m = -1e30f;
    for (int i = 0; i < WW; ++i) m = fmaxf(m, attw[i]);
    float ssum = 0.f;
    for (int i = 0; i < WW; ++i) { float e = __expf(attw[i] - m); aw_lds[i] = e; ssum += e; }
    float inv = 1.f / ssum;
    for (int i = 0; i < WW; ++i) aw_lds[i] *= inv;
    m = -1e30f;
    for (int i = 0; i < SS; ++i) m = fmaxf(m, atts[i]);
    ssum = 0.f;
    for (int i = 0; i < SS; ++i) { float e = __expf(atts[i] - m); as_lds[i] = e; ssum += e; }
    inv = 1.f / ssum;
    for (int i = 0; i < SS; ++i) as_lds[i] *= inv;
  }
  if (tid < 4) {
    c_lds[tid]   = c1_0[u0 + tid];
    enc_lds[tid] = 0.f;
    row_lds[tid] = 0.f;
  }

  // wih1 -> LDS (once). local gate-row r (0..15): gate=r>>2, unit j=r&3,
  // global row = (r>>2)*1024 + u0 + (r&3).
  for (int q = 0; q < 32; ++q) {
    const int idx = (q << 9) + tid;          // 0..16383
    const int r = idx >> 10, col = idx & 1023;
    const int grow = ((r >> 2) << 10) + u0 + (r & 3);
    wih_lds[idx] = Wih1[(size_t)grow * 1024 + col];
  }

  // whh1 -> registers (32 floats/thread): rows r0=2wv, r1=2wv+1, cols jj*64+l
  float whh[2][16], bias[2];
#pragma unroll
  for (int t = 0; t < 2; ++t) {
    const int r    = (wv << 1) + t;
    const int grow = ((r >> 2) << 10) + u0 + (r & 3);
    bias[t] = bih1[grow] + bhh1[grow];
    const float* phh = Whh1 + (size_t)grow * 1024 + l;
#pragma unroll
    for (int jj = 0; jj < 16; ++jj) whh[t][jj] = phh[jj * 64];
  }
#pragma unroll
  for (int t = 0; t < 2; ++t)
#pragma unroll
    for (int jj = 0; jj < 16; ++jj) asm volatile("" : "+v"(whh[t][jj]));
  __syncthreads();

  const int r0 = (wv << 1), r1 = r0 + 1;

  // ======================= layer 1: 8192 word steps =======================
  for (int k = 0; k < T1; ++k) {
    // x-row load + x-partial from LDS wih — entirely pre-gate (off critical path)
    const float* xrow = xin + (size_t)k * 1024 + l;
    float xv[16];
#pragma unroll
    for (int jj = 0; jj < 16; ++jj) xv[jj] = xrow[jj * 64];
    float xa0 = 0.f, xa1 = 0.f;
#pragma unroll
    for (int jj = 0; jj < 16; ++jj) {
      const float x = xv[jj];
      xa0 += wih_lds[(r0 << 10) + (jj << 6) + l] * x;
      xa1 += wih_lds[(r1 << 10) + (jj << 6) + l] * x;
    }

    if (k > 0) {
      gate_wait(cells, (unsigned)k, wv, l, &go);
      READ2_VERIFY(hbuf64 + ((size_t)(k & 1) << 10), k, h_lds);
    } else {
      h_lds[tid]       = h1_0[tid];
      h_lds[512 + tid] = h1_0[512 + tid];
    }
    __syncthreads();   // B1: h_lds ready

    float a0 = xa0, a1 = xa1;
#pragma unroll
    for (int jj = 0; jj < 16; ++jj) {
      const float hv = h_lds[(jj << 6) + l];
      a0 += whh[0][jj] * hv; a1 += whh[1][jj] * hv;
    }
#pragma unroll
    for (int m = 1; m < 64; m <<= 1) {
      a0 += __shfl_xor(a0, m); a1 += __shfl_xor(a1, m);
    }
    if (l == 0) {
      g_lds[r0] = a0 + bias[0];
      g_lds[r1] = a1 + bias[1];
    }
    __syncthreads();   // B2: g_lds ready; all step-k LDS reads done
    if (tid < 4) {                       // torch gate order: i,f,g,o
      const int j = tid;
      const float ig = g_lds[0 + j], fg = g_lds[4 + j], gg = g_lds[8 + j], og = g_lds[12 + j];
      const float si = 1.f / (1.f + __expf(-ig));
      const float sf = 1.f / (1.f + __expf(-fg));
      const float so = 1.f / (1.f + __expf(-og));
      const float c  = sf * c_lds[j] + si * tanhf(gg);
      const float h  = so * tanhf(c);
      c_lds[j] = c;
      const int wd = k & (WW - 1);
      float e = enc_lds[j] + aw_lds[wd] * h;          // enc = aw @ hs (online)
      u64* dst = hbuf64 + ((size_t)((k + 1) & 1) << 10);
      astore(&dst[u0 + j], pack(h, (unsigned)(k + 1)));
      if (wd == WW - 1) {
        astore(&encs64[((size_t)(k >> 7) << 10) + u0 + j], pack(e, (unsigned)((k >> 7) + 1)));
        e = 0.f;
      }
      enc_lds[j] = e;
    }
    if (tid == 0)   // completion signal; tags cover store/add completion races
      __hip_atomic_fetch_add(&cells[(size_t)(wid >> 5) << 3], 1ull,
                             __ATOMIC_RELAXED, __HIP_MEMORY_SCOPE_AGENT);
    // no trailing barrier: gate k+1 (cells>=32(k+1)) implies every WG finished
    // step-k reads, so h_lds/g_lds overwrites for k+1 are safe.
  }

  // ======================= layer 2: 64 sentence steps =======================
  for (int q = 0; q < 32; ++q) {         // wih2 -> LDS (safe: all wih reads done pre-B2 of k=8191)
    const int idx = (q << 9) + tid;
    const int r = idx >> 10, col = idx & 1023;
    const int grow = ((r >> 2) << 10) + u0 + (r & 3);
    wih_lds[idx] = Wih2[(size_t)grow * 1024 + col];
  }
#pragma unroll
  for (int t = 0; t < 2; ++t) {          // whh2 -> same registers
    const int r    = (wv << 1) + t;
    const int grow = ((r >> 2) << 10) + u0 + (r & 3);
    bias[t] = bih2[grow] + bhh2[grow];
    const float* phh = Whh2 + (size_t)grow * 1024 + l;
#pragma unroll
    for (int jj = 0; jj < 16; ++jj) whh[t][jj] = phh[jj * 64];
  }
#pragma unroll
  for (int t = 0; t < 2; ++t)
#pragma unroll
    for (int jj = 0; jj < 16; ++jj) asm volatile("" : "+v"(whh[t][jj]));
  if (tid < 4) c_lds[tid] = c2_0[u0 + tid];   // wave 0 only, after its last epilogue

  for (int s2 = 0; s2 < SS; ++s2) {
    const unsigned kg = (unsigned)(T1 + s2);
    // enc row: written back in layer 1, tag s2+1 — ancient, verify passes at once
    READ2_VERIFY(encs64 + ((size_t)s2 << 10), s2 + 1, e_lds);
    __syncthreads();   // e_lds ready (and, at s2=0, wih2/c2 ready)

    float xa0 = 0.f, xa1 = 0.f;
#pragma unroll
    for (int jj = 0; jj < 16; ++jj) {
      const float ev = e_lds[(jj << 6) + l];
      xa0 += wih_lds[(r0 << 10) + (jj << 6) + l] * ev;
      xa1 += wih_lds[(r1 << 10) + (jj << 6) + l] * ev;
    }

    // gate: s2==0 waits 32*8192 (all layer-1 reads done -> slot overwrite safe)
    gate_wait(cells, kg, wv, l, &go);
    if (s2 > 0) {
      READ2_VERIFY(hbuf64 + ((size_t)(kg & 1) << 10), kg, h_lds);
    } else {
      h_lds[tid]       = h2_0[tid];
      h_lds[512 + tid] = h2_0[512 + tid];
    }
    __syncthreads();   // B1

    float a0 = xa0, a1 = xa1;
#pragma unroll
    for (int jj = 0; jj < 16; ++jj) {
      const float hv = h_lds[(jj << 6) + l];
      a0 += whh[0][jj] * hv; a1 += whh[1][jj] * hv;
    }
#pragma unroll
    for (int m = 1; m < 64; m <<= 1) {
      a0 += __shfl_xor(a0, m); a1 += __shfl_xor(a1, m);
    }
    if (l == 0) {
      g_lds[r0] = a0 + bias[0];
      g_lds[r1] = a1 + bias[1];
    }
    __syncthreads();   // B2
    if (tid < 4) {
      const int j = tid;
      const float ig = g_lds[0 + j], fg = g_lds[4 + j], gg = g_lds[8 + j], og = g_lds[12 + j];
      const float si = 1.f / (1.f + __expf(-ig));
      const float sf = 1.f / (1.f + __expf(-fg));
      const float so = 1.f / (1.f + __expf(-og));
      const float c  = sf * c_lds[j] + si * tanhf(gg);
      const float h  = so * tanhf(c);
      c_lds[j] = c;
      row_lds[j] += as_lds[s2] * h;                    // row = asn @ hs2 (online)
      u64* dst = hbuf64 + ((size_t)((kg + 1) & 1) << 10);
      astore(&dst[u0 + j], pack(h, kg + 1));
    }
    if (tid == 0)
      __hip_atomic_fetch_add(&cells[(size_t)(wid >> 5) << 3], 1ull,
                             __ATOMIC_RELAXED, __HIP_MEMORY_SCOPE_AGENT);
  }

  // =================== final projection + sigmoid ===================
  if (tid == 0) {
    const float p = row_lds[0] * Wf[u0 + 0] + row_lds[1] * Wf[u0 + 1]
                  + row_lds[2] * Wf[u0 + 2] + row_lds[3] * Wf[u0 + 3];
    astore(&part64[wid], pack(p, 1u));
  }
  if (wid == 0) {
    if (tid < 256) {
      u64 a;
      for (;;) { a = aload(&part64[tid]); if ((unsigned)(a >> 32) == 1u) break; }
      h_lds[tid] = __uint_as_float((unsigned)a);
    }
    __syncthreads();
    if (wv == 0) {
      float p = h_lds[l] + h_lds[64 + l] + h_lds[128 + l] + h_lds[192 + l];
#pragma unroll
      for (int m = 1; m < 64; m <<= 1) p += __shfl_xor(p, m);
      if (l == 0) out[0] = 1.f / (1.f + __expf(-(p + bfb[0])));
    }
  }
}

extern "C" void kernel_launch(void* const* d_in, const int* in_sizes, int n_in,
                              void* d_out, int out_size, void* d_ws, size_t ws_size,
                              hipStream_t stream) {
  (void)in_sizes; (void)n_in; (void)out_size; (void)ws_size;
  const float* xin  = (const float*)d_in[0];
  const float* h1   = (const float*)d_in[1];
  const float* c1   = (const float*)d_in[2];
  const float* h2   = (const float*)d_in[3];
  const float* c2   = (const float*)d_in[4];
  const float* Wih1 = (const float*)d_in[5];
  const float* Whh1 = (const float*)d_in[6];
  const float* bih1 = (const float*)d_in[7];
  const float* bhh1 = (const float*)d_in[8];
  const float* Wih2 = (const float*)d_in[9];
  const float* Whh2 = (const float*)d_in[10];
  const float* bih2 = (const float*)d_in[11];
  const float* bhh2 = (const float*)d_in[12];
  const float* attw = (const float*)d_in[13];
  const float* atts = (const float*)d_in[14];
  const float* Wf   = (const float*)d_in[15];
  const float* bfb  = (const float*)d_in[16];

  u64* hbuf64 = (u64*)d_ws;                 // 2048 u64
  u64* encs64 = hbuf64 + 2048;              // 65536 u64
  u64* part64 = encs64 + 65536;             // 256 u64
  u64* cells  = part64 + 256;               // 64 u64 (8 cells, 64B apart)
  float* out  = (float*)d_out;

  // tags/counters must start at 0 every call — replay-safe, graph-capture legal
  hipMemsetAsync(d_ws, 0, (2048 + 65536 + 256 + 64) * sizeof(u64), stream);
  lstm_hier_attn<<<dim3(NWG), dim3(NTH), 0, stream>>>(
      xin, h1, c1, h2, c2, Wih1, Whh1, bih1, bhh1,
      Wih2, Whh2, bih2, bhh2, attw, atts, Wf, bfb,
      hbuf64, encs64, part64, cells, out);
}

// Round 6
// 45190.607 us; speedup vs baseline: 1.5573x; 1.4908x over previous
//
#include <hip/hip_runtime.h>
#include <hip/hip_bf16.h>

#define NWG 256   // persistent workgroups == #CUs; each owns 4 hidden units
#define NTH 512   // 8 waves; wave w owns gate-rows 2w,2w+1; wave 7 is the poller
#define T1  8192  // S*W word steps
#define SS  64
#define WW  128

typedef unsigned long long u64;
typedef unsigned int u32x4 __attribute__((ext_vector_type(4)));

// ws layout: [0..2047] hbuf64 (2 slots x 1024 tagged h),
// [2048..67583] encs64 (64 x 1024 tagged), [67584..67839] part64 (256 tagged),
// then 256 u32 flags (1KB). memset 0 each call (tag/flag 0 == invalid).

__device__ __forceinline__ u64 aload(const u64* p) {
  return __hip_atomic_load(p, __ATOMIC_RELAXED, __HIP_MEMORY_SCOPE_AGENT);
}
__device__ __forceinline__ void astore(u64* p, u64 v) {
  __hip_atomic_store(p, v, __ATOMIC_RELAXED, __HIP_MEMORY_SCOPE_AGENT);
}
__device__ __forceinline__ void astore32(unsigned* p, unsigned v) {
  __hip_atomic_store(p, v, __ATOMIC_RELAXED, __HIP_MEMORY_SCOPE_AGENT);
}
__device__ __forceinline__ u64 pack(float v, unsigned tag) {
  return ((u64)tag << 32) | (u64)__float_as_uint(v);
}

// 16B AGENT-scope load: sc1 bypasses the non-coherent XCD L2, served by LLC.
__device__ __forceinline__ u32x4 load16_agent(const void* p) {
  u32x4 r;
  asm volatile("global_load_dwordx4 %0, %1, off sc1\n\ts_waitcnt vmcnt(0)"
               : "=&v"(r) : "v"(p) : "memory");
  return r;
}

// one-shot tagged read of this thread's 2 columns (2*tid, 2*tid+1) + deposit.
// u64 little-endian: dwords = [val, tag]; v4 = [val0, tag0, val1, tag1].
#define READ2_VERIFY(BASE, TAG, DST) do {                                 \
    const u64* _q = (BASE) + ((size_t)tid << 1);                          \
    const unsigned _t = (unsigned)(TAG);                                  \
    u32x4 _r;                                                             \
    for (;;) { _r = load16_agent(_q); if (__builtin_expect(_r.y == _t && _r.w == _t, 1)) break; } \
    (DST)[(tid << 1) + 0] = __uint_as_float(_r.x);                        \
    (DST)[(tid << 1) + 1] = __uint_as_float(_r.z);                        \
  } while (0)

// wave 7: one dwordx4/lane covers all 256 per-WG flags; LDS go fanout.
// NO atomic RMW anywhere (R4/R5: agent fetch_add = serialized HBM RMW, 3-5x).
__device__ __forceinline__ void gate_wait(const unsigned* flags, unsigned k,
                                          int wv, int l, int* goP) {
  if (wv == 7) {
    const unsigned* p = flags + (l << 2);
    for (;;) {
      u32x4 f = load16_agent(p);
      if (__all(f.x >= k && f.y >= k && f.z >= k && f.w >= k)) break;
    }
    if (l == 0)
      __hip_atomic_store(goP, (int)k, __ATOMIC_RELAXED, __HIP_MEMORY_SCOPE_WORKGROUP);
  } else {
    while (__hip_atomic_load(goP, __ATOMIC_RELAXED, __HIP_MEMORY_SCOPE_WORKGROUP) < (int)k) {}
  }
}

__global__ __launch_bounds__(NTH) __attribute__((amdgpu_waves_per_eu(2, 2)))
void lstm_hier_attn(const float* __restrict__ xin,
                    const float* __restrict__ h1_0, const float* __restrict__ c1_0,
                    const float* __restrict__ h2_0, const float* __restrict__ c2_0,
                    const float* __restrict__ Wih1, const float* __restrict__ Whh1,
                    const float* __restrict__ bih1, const float* __restrict__ bhh1,
                    const float* __restrict__ Wih2, const float* __restrict__ Whh2,
                    const float* __restrict__ bih2, const float* __restrict__ bhh2,
                    const float* __restrict__ attw, const float* __restrict__ atts,
                    const float* __restrict__ Wf,   const float* __restrict__ bfb,
                    u64* hbuf64, u64* encs64, u64* part64, unsigned* flags,
                    float* out)
{
  const int wid = blockIdx.x;
  const int tid = threadIdx.x;
  const int wv  = tid >> 6;   // wave id 0..7
  const int l   = tid & 63;   // lane
  const int u0  = wid << 2;   // first hidden unit owned by this WG

  __shared__ float wih_lds[16 * 1024];   // 64KB: x-weights (16 gate rows x 1024)
  __shared__ float h_lds[1024];
  __shared__ float e_lds[1024];
  __shared__ float aw_lds[WW];
  __shared__ float as_lds[SS];
  __shared__ float g_lds[16];
  __shared__ float c_lds[4];
  __shared__ float enc_lds[4];
  __shared__ float row_lds[4];
  __shared__ int go;

  if (tid == 0) {   // one-time softmaxes
    go = 0;
    float m = -1e30f;
    for (int i = 0; i < WW; ++i) m = fmaxf(m, attw[i]);
    float ssum = 0.f;
    for (int i = 0; i < WW; ++i) { float e = __expf(attw[i] - m); aw_lds[i] = e; ssum += e; }
    float inv = 1.f / ssum;
    for (int i = 0; i < WW; ++i) aw_lds[i] *= inv;
    m = -1e30f;
    for (int i = 0; i < SS; ++i) m = fmaxf(m, atts[i]);
    ssum = 0.f;
    for (int i = 0; i < SS; ++i) { float e = __expf(atts[i] - m); as_lds[i] = e; ssum += e; }
    inv = 1.f / ssum;
    for (int i = 0; i < SS; ++i) as_lds[i] *= inv;
  }
  if (tid < 4) {
    c_lds[tid]   = c1_0[u0 + tid];
    enc_lds[tid] = 0.f;
    row_lds[tid] = 0.f;
  }

  // wih1 -> LDS (once). local gate-row r (0..15): gate=r>>2, unit j=r&3,
  // global row = (r>>2)*1024 + u0 + (r&3).
  for (int q = 0; q < 32; ++q) {
    const int idx = (q << 9) + tid;          // 0..16383
    const int r = idx >> 10, col = idx & 1023;
    const int grow = ((r >> 2) << 10) + u0 + (r & 3);
    wih_lds[idx] = Wih1[(size_t)grow * 1024 + col];
  }

  // whh1 -> registers (32 floats/thread): rows r0=2wv, r1=2wv+1, cols jj*64+l
  float whh[2][16], bias[2];
#pragma unroll
  for (int t = 0; t < 2; ++t) {
    const int r    = (wv << 1) + t;
    const int grow = ((r >> 2) << 10) + u0 + (r & 3);
    bias[t] = bih1[grow] + bhh1[grow];
    const float* phh = Whh1 + (size_t)grow * 1024 + l;
#pragma unroll
    for (int jj = 0; jj < 16; ++jj) whh[t][jj] = phh[jj * 64];
  }
#pragma unroll
  for (int t = 0; t < 2; ++t)
#pragma unroll
    for (int jj = 0; jj < 16; ++jj) asm volatile("" : "+v"(whh[t][jj]));
  __syncthreads();

  const int r0 = (wv << 1), r1 = r0 + 1;

  // ======================= layer 1: 8192 word steps =======================
  for (int k = 0; k < T1; ++k) {
    // x-row load + x-partial from LDS wih — entirely pre-gate (off critical path)
    const float* xrow = xin + (size_t)k * 1024 + l;
    float xv[16];
#pragma unroll
    for (int jj = 0; jj < 16; ++jj) xv[jj] = xrow[jj * 64];
    float xa0 = 0.f, xa1 = 0.f;
#pragma unroll
    for (int jj = 0; jj < 16; ++jj) {
      const float x = xv[jj];
      xa0 += wih_lds[(r0 << 10) + (jj << 6) + l] * x;
      xa1 += wih_lds[(r1 << 10) + (jj << 6) + l] * x;
    }

    if (k > 0) {
      gate_wait(flags, (unsigned)k, wv, l, &go);
      READ2_VERIFY(hbuf64 + ((size_t)(k & 1) << 10), k, h_lds);
    } else {
      h_lds[tid]       = h1_0[tid];
      h_lds[512 + tid] = h1_0[512 + tid];
    }
    __syncthreads();   // B1: h_lds ready

    float a0 = xa0, a1 = xa1;
#pragma unroll
    for (int jj = 0; jj < 16; ++jj) {
      const float hv = h_lds[(jj << 6) + l];
      a0 += whh[0][jj] * hv; a1 += whh[1][jj] * hv;
    }
#pragma unroll
    for (int m = 1; m < 64; m <<= 1) {
      a0 += __shfl_xor(a0, m); a1 += __shfl_xor(a1, m);
    }
    if (l == 0) {
      g_lds[r0] = a0 + bias[0];
      g_lds[r1] = a1 + bias[1];
    }
    __syncthreads();   // B2: g_lds ready; all step-k LDS reads done
    if (tid < 4) {                       // torch gate order: i,f,g,o
      const int j = tid;
      const float ig = g_lds[0 + j], fg = g_lds[4 + j], gg = g_lds[8 + j], og = g_lds[12 + j];
      const float si = 1.f / (1.f + __expf(-ig));
      const float sf = 1.f / (1.f + __expf(-fg));
      const float so = 1.f / (1.f + __expf(-og));
      const float c  = sf * c_lds[j] + si * tanhf(gg);
      const float h  = so * tanhf(c);
      c_lds[j] = c;
      const int wd = k & (WW - 1);
      float e = enc_lds[j] + aw_lds[wd] * h;          // enc = aw @ hs (online)
      u64* dst = hbuf64 + ((size_t)((k + 1) & 1) << 10);
      astore(&dst[u0 + j], pack(h, (unsigned)(k + 1)));
      if (wd == WW - 1) {
        astore(&encs64[((size_t)(k >> 7) << 10) + u0 + j], pack(e, (unsigned)((k >> 7) + 1)));
        e = 0.f;
      }
      enc_lds[j] = e;
      if (j == 0) astore32(&flags[wid], (unsigned)(k + 1));  // plain store, no RMW;
      // issued after h stores in wave program order; tags cover completion races
    }
    // no trailing barrier: gate k+1 (all flags>=k+1) implies every WG finished
    // step-k reads, so h_lds/g_lds overwrites for k+1 are safe.
  }

  // ======================= layer 2: 64 sentence steps =======================
  for (int q = 0; q < 32; ++q) {         // wih2 -> LDS (safe: all wih reads done pre-B2 of k=8191)
    const int idx = (q << 9) + tid;
    const int r = idx >> 10, col = idx & 1023;
    const int grow = ((r >> 2) << 10) + u0 + (r & 3);
    wih_lds[idx] = Wih2[(size_t)grow * 1024 + col];
  }
#pragma unroll
  for (int t = 0; t < 2; ++t) {          // whh2 -> same registers
    const int r    = (wv << 1) + t;
    const int grow = ((r >> 2) << 10) + u0 + (r & 3);
    bias[t] = bih2[grow] + bhh2[grow];
    const float* phh = Whh2 + (size_t)grow * 1024 + l;
#pragma unroll
    for (int jj = 0; jj < 16; ++jj) whh[t][jj] = phh[jj * 64];
  }
#pragma unroll
  for (int t = 0; t < 2; ++t)
#pragma unroll
    for (int jj = 0; jj < 16; ++jj) asm volatile("" : "+v"(whh[t][jj]));
  if (tid < 4) c_lds[tid] = c2_0[u0 + tid];   // wave 0, after its last epilogue

  for (int s2 = 0; s2 < SS; ++s2) {
    const unsigned kg = (unsigned)(T1 + s2);
    // enc row: written back in layer 1, tag s2+1 — ancient, verify passes at once
    READ2_VERIFY(encs64 + ((size_t)s2 << 10), s2 + 1, e_lds);
    __syncthreads();   // e_lds ready (and, at s2=0, wih2/c2 ready)

    float xa0 = 0.f, xa1 = 0.f;
#pragma unroll
    for (int jj = 0; jj < 16; ++jj) {
      const float ev = e_lds[(jj << 6) + l];
      xa0 += wih_lds[(r0 << 10) + (jj << 6) + l] * ev;
      xa1 += wih_lds[(r1 << 10) + (jj << 6) + l] * ev;
    }

    // gate: s2==0 waits flags>=8192 (all layer-1 reads done -> overwrite safe)
    gate_wait(flags, kg, wv, l, &go);
    if (s2 > 0) {
      READ2_VERIFY(hbuf64 + ((size_t)(kg & 1) << 10), kg, h_lds);
    } else {
      h_lds[tid]       = h2_0[tid];
      h_lds[512 + tid] = h2_0[512 + tid];
    }
    __syncthreads();   // B1

    float a0 = xa0, a1 = xa1;
#pragma unroll
    for (int jj = 0; jj < 16; ++jj) {
      const float hv = h_lds[(jj << 6) + l];
      a0 += whh[0][jj] * hv; a1 += whh[1][jj] * hv;
    }
#pragma unroll
    for (int m = 1; m < 64; m <<= 1) {
      a0 += __shfl_xor(a0, m); a1 += __shfl_xor(a1, m);
    }
    if (l == 0) {
      g_lds[r0] = a0 + bias[0];
      g_lds[r1] = a1 + bias[1];
    }
    __syncthreads();   // B2
    if (tid < 4) {
      const int j = tid;
      const float ig = g_lds[0 + j], fg = g_lds[4 + j], gg = g_lds[8 + j], og = g_lds[12 + j];
      const float si = 1.f / (1.f + __expf(-ig));
      const float sf = 1.f / (1.f + __expf(-fg));
      const float so = 1.f / (1.f + __expf(-og));
      const float c  = sf * c_lds[j] + si * tanhf(gg);
      const float h  = so * tanhf(c);
      c_lds[j] = c;
      row_lds[j] += as_lds[s2] * h;                    // row = asn @ hs2 (online)
      u64* dst = hbuf64 + ((size_t)((kg + 1) & 1) << 10);
      astore(&dst[u0 + j], pack(h, kg + 1));
      if (j == 0) astore32(&flags[wid], kg + 1);
    }
  }

  // =================== final projection + sigmoid ===================
  if (tid == 0) {
    const float p = row_lds[0] * Wf[u0 + 0] + row_lds[1] * Wf[u0 + 1]
                  + row_lds[2] * Wf[u0 + 2] + row_lds[3] * Wf[u0 + 3];
    astore(&part64[wid], pack(p, 1u));
  }
  if (wid == 0) {
    if (tid < 256) {
      u64 a;
      for (;;) { a = aload(&part64[tid]); if ((unsigned)(a >> 32) == 1u) break; }
      h_lds[tid] = __uint_as_float((unsigned)a);
    }
    __syncthreads();
    if (wv == 0) {
      float p = h_lds[l] + h_lds[64 + l] + h_lds[128 + l] + h_lds[192 + l];
#pragma unroll
      for (int m = 1; m < 64; m <<= 1) p += __shfl_xor(p, m);
      if (l == 0) out[0] = 1.f / (1.f + __expf(-(p + bfb[0])));
    }
  }
}

extern "C" void kernel_launch(void* const* d_in, const int* in_sizes, int n_in,
                              void* d_out, int out_size, void* d_ws, size_t ws_size,
                              hipStream_t stream) {
  (void)in_sizes; (void)n_in; (void)out_size; (void)ws_size;
  const float* xin  = (const float*)d_in[0];
  const float* h1   = (const float*)d_in[1];
  const float* c1   = (const float*)d_in[2];
  const float* h2   = (const float*)d_in[3];
  const float* c2   = (const float*)d_in[4];
  const float* Wih1 = (const float*)d_in[5];
  const float* Whh1 = (const float*)d_in[6];
  const float* bih1 = (const float*)d_in[7];
  const float* bhh1 = (const float*)d_in[8];
  const float* Wih2 = (const float*)d_in[9];
  const float* Whh2 = (const float*)d_in[10];
  const float* bih2 = (const float*)d_in[11];
  const float* bhh2 = (const float*)d_in[12];
  const float* attw = (const float*)d_in[13];
  const float* atts = (const float*)d_in[14];
  const float* Wf   = (const float*)d_in[15];
  const float* bfb  = (const float*)d_in[16];

  u64* hbuf64 = (u64*)d_ws;                 // 2048 u64
  u64* encs64 = hbuf64 + 2048;              // 65536 u64
  u64* part64 = encs64 + 65536;             // 256 u64
  unsigned* flags = (unsigned*)(part64 + 256);  // 256 u32 (1KB)
  float* out  = (float*)d_out;

  // tags/flags must start at 0 every call — replay-safe, graph-capture legal
  hipMemsetAsync(d_ws, 0, (2048 + 65536 + 256) * sizeof(u64) + 256 * sizeof(unsigned), stream);
  lstm_hier_attn<<<dim3(NWG), dim3(NTH), 0, stream>>>(
      xin, h1, c1, h2, c2, Wih1, Whh1, bih1, bhh1,
      Wih2, Whh2, bih2, bhh2, attw, atts, Wf, bfb,
      hbuf64, encs64, part64, flags, out);
}

// Round 9
// 19583.734 us; speedup vs baseline: 3.5935x; 2.3076x over previous
//
#include <hip/hip_runtime.h>
#include <hip/hip_bf16.h>

#define NWG 256   // persistent workgroups == CUs; WG owns 4 hidden units
#define NTH 256   // 4 waves; wave j owns unit u0+j end-to-end (no cross-wave state)
#define T1  8192  // S*W word steps
#define SS  64
#define WW  128

typedef unsigned long long u64;
typedef unsigned int u32x4 __attribute__((ext_vector_type(4)));

// ws layout (8B units): [0..2047] hbuf64 (2 slots x 1024 tagged h),
// [2048..67583] encs64 (64 x 1024 tagged), [67584..67839] part64 (256 tagged).
// memset 0 each call (tag 0 == invalid; valid tags start at 1).
// ONLY proven primitives: agent-scope (sc1, LLC-served) loads/stores. No RMW
// in the loop (R4/R5), no flags (R6), no sc0/leader tricks (R7 hang).

__device__ __forceinline__ u64 aload(const u64* p) {
  return __hip_atomic_load(p, __ATOMIC_RELAXED, __HIP_MEMORY_SCOPE_AGENT);
}
__device__ __forceinline__ void astore(u64* p, u64 v) {
  __hip_atomic_store(p, v, __ATOMIC_RELAXED, __HIP_MEMORY_SCOPE_AGENT);
}
__device__ __forceinline__ u64 pack(float v, unsigned tag) {
  return ((u64)tag << 32) | (u64)__float_as_uint(v);
}

// two 16B agent-scope loads issued together, single wait (32B = 4 tagged cols)
// NOTE gfx950 operand order: offset: immediate BEFORE cache flags (R8 compile fix)
__device__ __forceinline__ void load32_sc1(const u64* p, u32x4& a, u32x4& b) {
  asm volatile("global_load_dwordx4 %0, %2, off sc1\n\t"
               "global_load_dwordx4 %1, %2, off offset:16 sc1\n\t"
               "s_waitcnt vmcnt(0)"
               : "=&v"(a), "=&v"(b) : "v"(p) : "memory");
}

// spin until this thread's 4 columns (4t..4t+3) carry TAG, deposit to DST+4t.
// u64 little-endian: dwords [val,tag]; vecs = [v0,t0,v1,t1].
#define SPIN4(BASE, TAG, DST) do {                                        \
    const u64* _q = (BASE) + ((size_t)tid << 2);                          \
    const unsigned _t = (unsigned)(TAG); u32x4 _a, _b;                    \
    for (;;) { load32_sc1(_q, _a, _b);                                    \
      if (__builtin_expect(_a.y == _t && _a.w == _t &&                    \
                           _b.y == _t && _b.w == _t, 1)) break; }         \
    float* _d = (DST) + (tid << 2);                                       \
    _d[0] = __uint_as_float(_a.x); _d[1] = __uint_as_float(_a.z);         \
    _d[2] = __uint_as_float(_b.x); _d[3] = __uint_as_float(_b.z);         \
  } while (0)

__global__ __launch_bounds__(NTH) __attribute__((amdgpu_waves_per_eu(1, 1)))
void lstm_hier_attn(const float* __restrict__ xin,
                    const float* __restrict__ h1_0, const float* __restrict__ c1_0,
                    const float* __restrict__ h2_0, const float* __restrict__ c2_0,
                    const float* __restrict__ Wih1, const float* __restrict__ Whh1,
                    const float* __restrict__ bih1, const float* __restrict__ bhh1,
                    const float* __restrict__ Wih2, const float* __restrict__ Whh2,
                    const float* __restrict__ bih2, const float* __restrict__ bhh2,
                    const float* __restrict__ attw, const float* __restrict__ atts,
                    const float* __restrict__ Wf,   const float* __restrict__ bfb,
                    u64* hbuf64, u64* encs64, u64* part64, float* out)
{
  const int wid = blockIdx.x;
  const int tid = threadIdx.x;
  const int wv  = tid >> 6;   // wave id 0..3 == owned unit index
  const int l   = tid & 63;
  const int u0  = wid << 2;

  __shared__ float wih_lds[16 * 1024];   // 64KB x-weights (gate-major rows)
  __shared__ float h_lds[2][1024];       // double-buffered by step parity
  __shared__ float e_lds[2][1024];       // double-buffered by sentence parity
  __shared__ float aw_lds[WW];
  __shared__ float as_lds[SS];
  __shared__ float fin_lds[4];

  if (tid == 0) {   // one-time softmaxes
    float m = -1e30f;
    for (int i = 0; i < WW; ++i) m = fmaxf(m, attw[i]);
    float ssum = 0.f;
    for (int i = 0; i < WW; ++i) { float e = __expf(attw[i] - m); aw_lds[i] = e; ssum += e; }
    float inv = 1.f / ssum;
    for (int i = 0; i < WW; ++i) aw_lds[i] *= inv;
    m = -1e30f;
    for (int i = 0; i < SS; ++i) m = fmaxf(m, atts[i]);
    ssum = 0.f;
    for (int i = 0; i < SS; ++i) { float e = __expf(atts[i] - m); as_lds[i] = e; ssum += e; }
    inv = 1.f / ssum;
    for (int i = 0; i < SS; ++i) as_lds[i] *= inv;
  }

  // wih1 -> LDS (once). row rr = gate*4 + unit; global row = gate*1024+u0+unit
  for (int q = 0; q < 64; ++q) {
    const int idx = (q << 8) + tid;          // 0..16383
    const int rr = idx >> 10, col = idx & 1023;
    wih_lds[idx] = Wih1[(size_t)(((rr >> 2) << 10) + u0 + (rr & 3)) * 1024 + col];
  }
  // whh1 -> registers: wave wv, rows gate g = 0..3 of unit u0+wv, cols l+64m
  float whh[4][16], bias[4];
#pragma unroll
  for (int g = 0; g < 4; ++g) {
    const int grow = (g << 10) + u0 + wv;
    bias[g] = bih1[grow] + bhh1[grow];
    const float* ph = Whh1 + (size_t)grow * 1024 + l;
#pragma unroll
    for (int m = 0; m < 16; ++m) whh[g][m] = ph[m << 6];
  }
#pragma unroll
  for (int g = 0; g < 4; ++g)
#pragma unroll
    for (int m = 0; m < 16; ++m) asm volatile("" : "+v"(whh[g][m]));

  float c   = c1_0[u0 + wv];   // unit state replicated across the wave's lanes
  float enc = 0.f, row = 0.f;
  const int rb0 = (0 + wv) << 10, rb1 = (4 + wv) << 10,
            rb2 = (8 + wv) << 10, rb3 = (12 + wv) << 10;
  __syncthreads();

  // ======================= layer 1: 8192 word steps =======================
  for (int k = 0; k < T1; ++k) {
    const int p = k & 1;
    // x-partial (pre-gate, off critical path): 4 gate rows of unit wv
    const float* xrow = xin + (size_t)k * 1024;
    float a0 = 0.f, a1 = 0.f, a2 = 0.f, a3 = 0.f;
#pragma unroll
    for (int m = 0; m < 16; ++m) {
      const int cix = (m << 6) + l;
      const float x = xrow[cix];
      a0 += wih_lds[rb0 + cix] * x; a1 += wih_lds[rb1 + cix] * x;
      a2 += wih_lds[rb2 + cix] * x; a3 += wih_lds[rb3 + cix] * x;
    }

    if (k > 0) { SPIN4(hbuf64 + ((size_t)p << 10), k, h_lds[p]); }
    else {
      const float* s = h1_0 + (tid << 2); float* d = h_lds[0] + (tid << 2);
      d[0] = s[0]; d[1] = s[1]; d[2] = s[2]; d[3] = s[3];
    }
    __syncthreads();   // B1 (only barrier/step): deposit done, reads safe;
                       // also licenses other-parity overwrite next step

    // h-GEMV from LDS (2-way bank = free), whh in VGPRs
#pragma unroll
    for (int m = 0; m < 16; ++m) {
      const float hv = h_lds[p][(m << 6) + l];
      a0 += whh[0][m] * hv; a1 += whh[1][m] * hv;
      a2 += whh[2][m] * hv; a3 += whh[3][m] * hv;
    }
#pragma unroll
    for (int mm = 1; mm < 64; mm <<= 1) {
      a0 += __shfl_xor(a0, mm); a1 += __shfl_xor(a1, mm);
      a2 += __shfl_xor(a2, mm); a3 += __shfl_xor(a3, mm);
    }
    // all lanes now hold the 4 gate sums of unit u0+wv; torch order i,f,g,o
    const float ig = a0 + bias[0], fg = a1 + bias[1];
    const float gg = a2 + bias[2], og = a3 + bias[3];
    const float si = 1.f / (1.f + __expf(-ig));
    const float sf = 1.f / (1.f + __expf(-fg));
    const float so = 1.f / (1.f + __expf(-og));
    c = sf * c + si * tanhf(gg);
    const float h = so * tanhf(c);
    if (l == 0)   // publish ASAP — this is the chip-wide critical path
      astore(&hbuf64[((size_t)((k + 1) & 1) << 10) + u0 + wv], pack(h, (unsigned)(k + 1)));
    const int wd = k & (WW - 1);
    const float e_new = enc + aw_lds[wd] * h;        // enc = aw @ hs (online)
    if (wd == WW - 1) {
      if (l == 0)
        astore(&encs64[((size_t)(k >> 7) << 10) + u0 + wv],
               pack(e_new, (unsigned)((k >> 7) + 1)));
      enc = 0.f;
    } else enc = e_new;
  }

  // ======================= layer 2: 64 sentence steps =======================
  __syncthreads();   // all wih1 reads done before overwrite
  for (int q = 0; q < 64; ++q) {
    const int idx = (q << 8) + tid;
    const int rr = idx >> 10, col = idx & 1023;
    wih_lds[idx] = Wih2[(size_t)(((rr >> 2) << 10) + u0 + (rr & 3)) * 1024 + col];
  }
#pragma unroll
  for (int g = 0; g < 4; ++g) {
    const int grow = (g << 10) + u0 + wv;
    bias[g] = bih2[grow] + bhh2[grow];
    const float* ph = Whh2 + (size_t)grow * 1024 + l;
#pragma unroll
    for (int m = 0; m < 16; ++m) whh[g][m] = ph[m << 6];
  }
#pragma unroll
  for (int g = 0; g < 4; ++g)
#pragma unroll
    for (int m = 0; m < 16; ++m) asm volatile("" : "+v"(whh[g][m]));
  c = c2_0[u0 + wv];

  for (int s2 = 0; s2 < SS; ++s2) {
    const unsigned kg = (unsigned)(T1 + s2);
    const int p = (int)(kg & 1), pe = s2 & 1;
    // enc row (tags ancient -> passes first try) then the h gate
    SPIN4(encs64 + ((size_t)s2 << 10), (unsigned)(s2 + 1), e_lds[pe]);
    // s2==0: spin for tag 8192 (slot-0 overwrite gate), then override with h2_0
    SPIN4(hbuf64 + ((size_t)p << 10), kg, h_lds[p]);
    if (s2 == 0) {
      const float* s = h2_0 + (tid << 2); float* d = h_lds[0] + (tid << 2);
      d[0] = s[0]; d[1] = s[1]; d[2] = s[2]; d[3] = s[3];
    }
    __syncthreads();   // B1 (covers wih2/c2 readiness at s2==0 too)

    float a0 = 0.f, a1 = 0.f, a2 = 0.f, a3 = 0.f;
#pragma unroll
    for (int m = 0; m < 16; ++m) {
      const int cix = (m << 6) + l;
      const float ev = e_lds[pe][cix];
      a0 += wih_lds[rb0 + cix] * ev; a1 += wih_lds[rb1 + cix] * ev;
      a2 += wih_lds[rb2 + cix] * ev; a3 += wih_lds[rb3 + cix] * ev;
      const float hv = h_lds[p][cix];
      a0 += whh[0][m] * hv; a1 += whh[1][m] * hv;
      a2 += whh[2][m] * hv; a3 += whh[3][m] * hv;
    }
#pragma unroll
    for (int mm = 1; mm < 64; mm <<= 1) {
      a0 += __shfl_xor(a0, mm); a1 += __shfl_xor(a1, mm);
      a2 += __shfl_xor(a2, mm); a3 += __shfl_xor(a3, mm);
    }
    const float ig = a0 + bias[0], fg = a1 + bias[1];
    const float gg = a2 + bias[2], og = a3 + bias[3];
    const float si = 1.f / (1.f + __expf(-ig));
    const float sf = 1.f / (1.f + __expf(-fg));
    const float so = 1.f / (1.f + __expf(-og));
    c = sf * c + si * tanhf(gg);
    const float h = so * tanhf(c);
    if (l == 0)
      astore(&hbuf64[((size_t)((kg + 1) & 1) << 10) + u0 + wv], pack(h, kg + 1u));
    row += as_lds[s2] * h;                           // row = asn @ hs2 (online)
  }

  // =================== final projection + sigmoid ===================
  if (l == 0) fin_lds[wv] = row * Wf[u0 + wv];
  __syncthreads();
  if (tid == 0)
    astore(&part64[wid],
           pack(fin_lds[0] + fin_lds[1] + fin_lds[2] + fin_lds[3], 1u));
  if (wid == 0) {
    u64 a;
    for (;;) { a = aload(&part64[tid]); if ((unsigned)(a >> 32) == 1u) break; }
    e_lds[0][tid] = __uint_as_float((unsigned)a);
    __syncthreads();
    if (wv == 0) {
      float pp = e_lds[0][l] + e_lds[0][64 + l] + e_lds[0][128 + l] + e_lds[0][192 + l];
#pragma unroll
      for (int mm = 1; mm < 64; mm <<= 1) pp += __shfl_xor(pp, mm);
      if (l == 0) out[0] = 1.f / (1.f + __expf(-(pp + bfb[0])));
    }
  }
}

extern "C" void kernel_launch(void* const* d_in, const int* in_sizes, int n_in,
                              void* d_out, int out_size, void* d_ws, size_t ws_size,
                              hipStream_t stream) {
  (void)in_sizes; (void)n_in; (void)out_size; (void)ws_size;
  const float* xin  = (const float*)d_in[0];
  const float* h1   = (const float*)d_in[1];
  const float* c1   = (const float*)d_in[2];
  const float* h2   = (const float*)d_in[3];
  const float* c2   = (const float*)d_in[4];
  const float* Wih1 = (const float*)d_in[5];
  const float* Whh1 = (const float*)d_in[6];
  const float* bih1 = (const float*)d_in[7];
  const float* bhh1 = (const float*)d_in[8];
  const float* Wih2 = (const float*)d_in[9];
  const float* Whh2 = (const float*)d_in[10];
  const float* bih2 = (const float*)d_in[11];
  const float* bhh2 = (const float*)d_in[12];
  const float* attw = (const float*)d_in[13];
  const float* atts = (const float*)d_in[14];
  const float* Wf   = (const float*)d_in[15];
  const float* bfb  = (const float*)d_in[16];

  u64* hbuf64 = (u64*)d_ws;                 // 2048 u64
  u64* encs64 = hbuf64 + 2048;              // 65536 u64
  u64* part64 = encs64 + 65536;             // 256 u64
  float* out  = (float*)d_out;

  // tags must start invalid (0) every call — replay-safe, graph-capture legal
  hipMemsetAsync(d_ws, 0, (2048 + 65536 + 256) * sizeof(u64), stream);
  lstm_hier_attn<<<dim3(NWG), dim3(NTH), 0, stream>>>(
      xin, h1, c1, h2, c2, Wih1, Whh1, bih1, bhh1,
      Wih2, Whh2, bih2, bhh2, attw, atts, Wf, bfb,
      hbuf64, encs64, part64, out);
}